// Round 4
// baseline (633.645 us; speedup 1.0000x reference)
//
#include <hip/hip_runtime.h>
#include <hip/hip_bf16.h>
#include <hip/hip_cooperative_groups.h>

namespace cg = cooperative_groups;
typedef __hip_bfloat16 bf16;

#define DEPS 1e-16f
#define CAP 32
#define OVF_MAX 131072

__device__ __forceinline__ float bfu_lo(unsigned u) { return __uint_as_float(u << 16); }
__device__ __forceinline__ float bfu_hi(unsigned u) { return __uint_as_float(u & 0xffff0000u); }

// bucket entry: (s << 15) | q, wt = q/8192 - 1.1, q in [0,32767]
__device__ __forceinline__ float dec_wt(unsigned u) {
    return (float)(u & 32767u) * (1.f / 8192.f) - 1.1f;
}

// ONE cooperative kernel, 5 phases separated by grid.sync():
//  P0: zero cnt/ovfn (replaces memset dispatch)
//  P1: hist over REAL edges (atomic rank) || gemm1 || self-loop scatter.
//      Self-loop owns reserved slot 0 of each bucket (order in bucket is
//      irrelevant to the softmax sum) -> no atomic for self-loops, and the
//      scatter is independent of hist so it rides in the atomic shadow.
//      Stripe 4:9 gemm:hist per R2 (gemm overlaps hist positively; NEVER
//      pair gemm with scat -- R3 showed that pairing is additive-negative).
//  P2: scatter real edges at slot 1+rank8[e] (atomic-free, full MLP)
//  P3: agg1 (layer-1 aggregate + slim layer-2 epilogue)
//  P4: agg2 (layer-2 aggregate + bias)
// Rationale: every kernel is <=90us but the 6-dispatch chain measured
// ~286us -> ~55us of inter-dispatch gap; grid.sync removes it.
__global__ __launch_bounds__(256) void f_mega(
    const float* __restrict__ x, const int* __restrict__ srcv,
    const int* __restrict__ dstv, const float* __restrict__ ew,
    const float* __restrict__ W1, const float* __restrict__ as1,
    const float* __restrict__ ad1, const float* __restrict__ b1,
    const float* __restrict__ W2, const float* __restrict__ a2s,
    const float* __restrict__ a2d, const float* __restrict__ b2,
    bf16* __restrict__ h1, unsigned* __restrict__ bkt,
    float* __restrict__ h2p, unsigned char* __restrict__ rank8,
    uint2* __restrict__ ovf, int* __restrict__ cnt, int* __restrict__ ovfn,
    float* __restrict__ asrc, float* __restrict__ adst, float* __restrict__ ad2,
    float* __restrict__ out, int N, int E, int T)
{
    cg::grid_group grid = cg::this_grid();
    __shared__ __align__(16) char smem[16896];   // phases overlay this
    int tid = threadIdx.x;
    int gid = blockIdx.x * 256 + tid;
    int nth = gridDim.x * 256;

    // ---------------- P0: zero cnt + ovfn ----------------
    for (int i = gid; i < N; i += nth) cnt[i] = 0;
    if (gid == 0) *ovfn = 0;
    grid.sync();

    // ---------------- P1: hist || gemm || self-loop scatter ----------------
    {
        float* xl = (float*)smem;                // 16 KB
        int gG = (N + 31) >> 5;
        int gH = (T + 255) >> 8;
        int chunks = max((gG + 3) / 4, (gH + 8) / 9);
        int V = chunks * 13;
        for (int vb = blockIdx.x; vb < V; vb += gridDim.x) {
            int r = vb % 13, chunk = vb / 13;
            if (r >= 4) {                        // hist role (9/13)
                int hb = chunk * 9 + (r - 4);
                if (hb >= gH) continue;
                int e = hb * 256 + tid;
                if (e >= T) continue;
                if (e < E) {
                    int d = dstv[e];
                    int pos = atomicAdd(&cnt[d], 1);
                    rank8[e] = (unsigned char)min(pos, 255);
                } else {                         // self-loop -> slot 0, no atomic
                    int d = e - E;
                    unsigned q = (unsigned)((0.f + 1.1f) * 8192.f + 0.5f);
                    bkt[(size_t)d * CAP] = ((unsigned)d << 15) | q;
                }
            } else {                             // gemm role (4/13), block-uniform
                int gb = chunk * 4 + r;
                if (gb >= gG) continue;
                int n0 = gb * 32;
                for (int i = tid; i < 1024; i += 256) {
                    int n = n0 + (i >> 5);
                    float4 v = {0.f, 0.f, 0.f, 0.f};
                    if (n < N) v = ((const float4*)x)[(size_t)n * 32 + (i & 31)];
                    ((float4*)xl)[i] = v;
                }
                __syncthreads();
                int wv = tid >> 6, c = tid & 63;
                float sa = as1[c], da = ad1[c];
                float acc[8] = {0.f, 0.f, 0.f, 0.f, 0.f, 0.f, 0.f, 0.f};
                const float* Wc = W1 + c;        // column ptr, stride 64; L2-resident
                for (int k4 = 0; k4 < 32; ++k4) {
                    float w0 = Wc[(4 * k4 + 0) * 64];
                    float w1 = Wc[(4 * k4 + 1) * 64];
                    float w2 = Wc[(4 * k4 + 2) * 64];
                    float w3 = Wc[(4 * k4 + 3) * 64];
                    #pragma unroll
                    for (int i = 0; i < 8; ++i) {
                        float4 xv = ((const float4*)(xl + (wv * 8 + i) * 128))[k4];
                        acc[i] = fmaf(xv.x, w0, fmaf(xv.y, w1,
                                 fmaf(xv.z, w2, fmaf(xv.w, w3, acc[i]))));
                    }
                }
                #pragma unroll
                for (int i = 0; i < 8; ++i) {
                    int n = n0 + wv * 8 + i;
                    float a = acc[i];
                    float ps = a * sa, pd = a * da;
                    #pragma unroll
                    for (int o = 32; o; o >>= 1) {
                        ps += __shfl_xor(ps, o);
                        pd += __shfl_xor(pd, o);
                    }
                    if (n < N) {
                        h1[(size_t)n * 64 + c] = __float2bfloat16(a);
                        if (c == 0) { asrc[n] = ps; adst[n] = pd; }
                    }
                }
                __syncthreads();                 // xl reused next vb iteration
            }
        }
    }
    grid.sync();

    // ---------------- P2: scatter real edges (slots 1..CAP-1) ----------------
    for (int e = gid; e < E; e += nth) {
        int s = srcv[e], d = dstv[e];
        float wt = 1.f - 1.f / ew[e];
        unsigned q = (unsigned)((wt + 1.1f) * 8192.f + 0.5f);
        unsigned entry = ((unsigned)s << 15) | q;
        int pos = 1 + (int)rank8[e];
        if (pos < CAP) {
            bkt[(size_t)d * CAP + pos] = entry;
        } else {
            int o = atomicAdd(ovfn, 1);          // ~tens of edges device-wide
            if (o < OVF_MAX) { uint2 v; v.x = (unsigned)d; v.y = entry; ovf[o] = v; }
        }
    }
    grid.sync();

    // ---------------- P3: agg1 + slim layer-2 epilogue ----------------
    {
        float (*WxT)[68] = (float(*)[68])smem;           // 4.25 KB
        float* b1l = (float*)(smem + 4352);              // 256 B
        float2 (*eb)[64] = (float2(*)[64])(smem + 4608); // 2 KB, wave-private
        if (tid < 64) {
            float us = 0.f, ud = 0.f;
            #pragma unroll
            for (int c = 0; c < 7; ++c) {
                float wv = W2[tid * 7 + c];
                WxT[c][tid] = wv;
                us = fmaf(wv, a2s[c], us);
                ud = fmaf(wv, a2d[c], ud);
            }
            WxT[7][tid] = us;
            WxT[8][tid] = ud;
            #pragma unroll
            for (int r = 9; r < 16; ++r) WxT[r][tid] = 0.f;
            b1l[tid] = b1[tid];
        }
        __syncthreads();
        int lane = tid & 63, wid = tid >> 6;
        int g8 = lane >> 3, l8 = lane & 7;
        float2* ebw = eb[wid];
        for (int dbase = blockIdx.x * 4; dbase < N; dbase += gridDim.x * 4) {
            int d = dbase + wid;                 // wave-uniform
            if (d >= N) continue;
            int lenf = cnt[d] + 1;               // +1: self-loop at slot 0
            int nc = min(lenf, CAP);
            size_t r0 = (size_t)d * CAP;
            float adv = adst[d];
            float acc[8] = {0.f, 0.f, 0.f, 0.f, 0.f, 0.f, 0.f, 0.f};
            float sm = 0.f;
            {
                float ea = 0.f; unsigned s = 0;
                if (lane < nc) {
                    unsigned u = bkt[r0 + lane];
                    s = u >> 15;
                    float a = asrc[s] + adv;
                    a = (a > 0.f) ? a : 0.2f * a;
                    ea = __expf(a + dec_wt(u));
                    sm += ea;
                }
                ebw[lane] = make_float2(ea, __uint_as_float(s));
                for (int j = 0; j < nc; j += 8) {
                    float2 eq = ebw[j + g8];     // 8-lane broadcast
                    float e = eq.x;              // padded slots have e==0
                    unsigned sj = __float_as_uint(eq.y);
                    uint4 hv = *(const uint4*)&h1[(size_t)sj * 64 + (l8 << 3)];
                    acc[0] = fmaf(e, bfu_lo(hv.x), acc[0]);
                    acc[1] = fmaf(e, bfu_hi(hv.x), acc[1]);
                    acc[2] = fmaf(e, bfu_lo(hv.y), acc[2]);
                    acc[3] = fmaf(e, bfu_hi(hv.y), acc[3]);
                    acc[4] = fmaf(e, bfu_lo(hv.z), acc[4]);
                    acc[5] = fmaf(e, bfu_hi(hv.z), acc[5]);
                    acc[6] = fmaf(e, bfu_lo(hv.w), acc[6]);
                    acc[7] = fmaf(e, bfu_hi(hv.w), acc[7]);
                }
            }
            if (lenf > CAP) {                    // rare overflow path
                int no = min(*ovfn, OVF_MAX);
                for (int i = g8; i < no; i += 8) {
                    uint2 ov = ovf[i];
                    if ((int)ov.x == d) {
                        unsigned u = ov.y;
                        unsigned s = u >> 15;
                        float a = asrc[s] + adv;
                        a = (a > 0.f) ? a : 0.2f * a;
                        float ea = __expf(a + dec_wt(u));
                        if (l8 == 0) sm += ea;   // count edge exactly once
                        uint4 hv = *(const uint4*)&h1[(size_t)s * 64 + (l8 << 3)];
                        acc[0] = fmaf(ea, bfu_lo(hv.x), acc[0]);
                        acc[1] = fmaf(ea, bfu_hi(hv.x), acc[1]);
                        acc[2] = fmaf(ea, bfu_lo(hv.y), acc[2]);
                        acc[3] = fmaf(ea, bfu_hi(hv.y), acc[3]);
                        acc[4] = fmaf(ea, bfu_lo(hv.z), acc[4]);
                        acc[5] = fmaf(ea, bfu_hi(hv.z), acc[5]);
                        acc[6] = fmaf(ea, bfu_lo(hv.w), acc[6]);
                        acc[7] = fmaf(ea, bfu_hi(hv.w), acc[7]);
                    }
                }
            }
            #pragma unroll
            for (int o = 32; o; o >>= 1) sm += __shfl_xor(sm, o);
            #pragma unroll
            for (int k = 0; k < 8; ++k) {
                acc[k] += __shfl_xor(acc[k], 8);
                acc[k] += __shfl_xor(acc[k], 16);
                acc[k] += __shfl_xor(acc[k], 32);
            }
            float inv = 1.f / (sm + DEPS);
            int c0 = l8 << 3;
            float4 bA = *(const float4*)&b1l[c0];
            float4 bB = *(const float4*)&b1l[c0 + 4];
            float v0 = fmaxf(fmaf(acc[0], inv, bA.x), 0.f);
            float v1 = fmaxf(fmaf(acc[1], inv, bA.y), 0.f);
            float v2 = fmaxf(fmaf(acc[2], inv, bA.z), 0.f);
            float v3 = fmaxf(fmaf(acc[3], inv, bA.w), 0.f);
            float v4 = fmaxf(fmaf(acc[4], inv, bB.x), 0.f);
            float v5 = fmaxf(fmaf(acc[5], inv, bB.y), 0.f);
            float v6 = fmaxf(fmaf(acc[6], inv, bB.z), 0.f);
            float v7 = fmaxf(fmaf(acc[7], inv, bB.w), 0.f);
            float4 wA0 = *(const float4*)&WxT[g8][c0];
            float4 wA1 = *(const float4*)&WxT[g8][c0 + 4];
            float4 wB0 = *(const float4*)&WxT[g8 + 8][c0];
            float4 wB1 = *(const float4*)&WxT[g8 + 8][c0 + 4];
            float rA = fmaf(v0, wA0.x, fmaf(v1, wA0.y, fmaf(v2, wA0.z, fmaf(v3, wA0.w,
                       fmaf(v4, wA1.x, fmaf(v5, wA1.y, fmaf(v6, wA1.z, v7 * wA1.w)))))));
            float rB = fmaf(v0, wB0.x, fmaf(v1, wB0.y, fmaf(v2, wB0.z, fmaf(v3, wB0.w,
                       fmaf(v4, wB1.x, fmaf(v5, wB1.y, fmaf(v6, wB1.z, v7 * wB1.w)))))));
            rA += __shfl_xor(rA, 1); rA += __shfl_xor(rA, 2); rA += __shfl_xor(rA, 4);
            rB += __shfl_xor(rB, 1); rB += __shfl_xor(rB, 2); rB += __shfl_xor(rB, 4);
            if (l8 == 0) {
                h2p[(size_t)d * 8 + g8] = rA;    // slots 0..6 = h2, 7 = as2
                if (g8 == 0) ad2[d] = rB;        // output 8 = ad2
            }
        }
    }
    grid.sync();

    // ---------------- P4: agg2 + bias ----------------
    {
        float* b2l = (float*)smem;
        if (tid < 7) b2l[tid] = b2[tid];
        __syncthreads();
        int lane = tid & 63, wv = tid >> 6;
        int grp = lane >> 3, l8 = lane & 7;
        for (int dbase = blockIdx.x * 32; dbase < N; dbase += gridDim.x * 32) {
            int d = dbase + wv * 8 + grp;
            bool valid = d < N;
            int lenf = 0; float adv = 0.f;
            if (valid) { lenf = cnt[d] + 1; adv = ad2[d]; }
            int nc = min(lenf, CAP);
            size_t r0 = (size_t)d * CAP;
            float sm = 0.f;
            float a0 = 0.f, a1 = 0.f, a2 = 0.f, a3 = 0.f, a4 = 0.f, a5 = 0.f, a6 = 0.f;
            for (int p = l8; p < nc; p += 8) {
                unsigned u = bkt[r0 + p];
                int s = (int)(u >> 15);
                const float* hr = &h2p[(size_t)s * 8];
                float4 A = *(const float4*)hr;
                float4 B = *(const float4*)(hr + 4);
                float a = B.w + adv;
                a = (a > 0.f) ? a : 0.2f * a;
                float ea = __expf(a + dec_wt(u));
                sm += ea;
                a0 = fmaf(ea, A.x, a0); a1 = fmaf(ea, A.y, a1);
                a2 = fmaf(ea, A.z, a2); a3 = fmaf(ea, A.w, a3);
                a4 = fmaf(ea, B.x, a4); a5 = fmaf(ea, B.y, a5);
                a6 = fmaf(ea, B.z, a6);
            }
            if (lenf > CAP) {                    // rare overflow path
                int no = min(*ovfn, OVF_MAX);
                for (int i = l8; i < no; i += 8) {
                    uint2 ov = ovf[i];
                    if ((int)ov.x == d) {
                        unsigned u = ov.y;
                        int s = (int)(u >> 15);
                        const float* hr = &h2p[(size_t)s * 8];
                        float4 A = *(const float4*)hr;
                        float4 B = *(const float4*)(hr + 4);
                        float a = B.w + adv;
                        a = (a > 0.f) ? a : 0.2f * a;
                        float ea = __expf(a + dec_wt(u));
                        sm += ea;
                        a0 = fmaf(ea, A.x, a0); a1 = fmaf(ea, A.y, a1);
                        a2 = fmaf(ea, A.z, a2); a3 = fmaf(ea, A.w, a3);
                        a4 = fmaf(ea, B.x, a4); a5 = fmaf(ea, B.y, a5);
                        a6 = fmaf(ea, B.z, a6);
                    }
                }
            }
            #pragma unroll
            for (int o = 4; o; o >>= 1) {
                sm += __shfl_xor(sm, o);
                a0 += __shfl_xor(a0, o); a1 += __shfl_xor(a1, o);
                a2 += __shfl_xor(a2, o); a3 += __shfl_xor(a3, o);
                a4 += __shfl_xor(a4, o); a5 += __shfl_xor(a5, o);
                a6 += __shfl_xor(a6, o);
            }
            if (valid && l8 < 7) {
                float inv = 1.f / (sm + DEPS);
                float val = (l8 < 4) ? ((l8 < 2) ? (l8 ? a1 : a0) : ((l8 == 2) ? a2 : a3))
                                     : ((l8 < 6) ? ((l8 == 4) ? a4 : a5) : a6);
                out[(size_t)d * 7 + l8] = fmaf(val, inv, b2l[l8]);
            }
        }
    }
}

// ============================== HOST ======================================

extern "C" void kernel_launch(void* const* d_in, const int* in_sizes, int n_in,
                              void* d_out, int out_size, void* d_ws, size_t ws_size,
                              hipStream_t stream) {
    const float* x   = (const float*)d_in[0];
    const int*   ei  = (const int*)d_in[1];
    const float* ew  = (const float*)d_in[2];
    const float* W1  = (const float*)d_in[3];
    const float* as1 = (const float*)d_in[4];
    const float* ad1 = (const float*)d_in[5];
    const float* b1  = (const float*)d_in[6];
    const float* W2  = (const float*)d_in[7];
    const float* a2s = (const float*)d_in[8];
    const float* a2d = (const float*)d_in[9];
    const float* b2  = (const float*)d_in[10];

    int N = in_sizes[0] / 128;
    int E = in_sizes[1] / 2;
    int T = E + N;
    const int* srcv = ei;
    const int* dstv = ei + E;
    float* out = (float*)d_out;

    // workspace (256B aligned): ~31.45 MB.
    // rank8 (u8, E bytes ~1.6MB) ALIASES h2p: written P1, read P2, and h2p
    // is first written in P3 (grid.sync-separated). h1 standalone.
    size_t A = 0;
    auto take = [&](size_t b) { size_t o = A; A = (A + b + 255) & ~(size_t)255; return o; };
    size_t o_h1   = take((size_t)N * 64 * 2);       // 12.8 MB
    size_t o_bkt  = take((size_t)N * CAP * 4);      // 12.8 MB
    size_t o_h2p  = take((size_t)N * 8 * 4);        //  3.2 MB (rank8 aliases)
    size_t o_ovf  = take((size_t)OVF_MAX * 8);      //  1.0 MB
    size_t o_cnt  = take((size_t)N * 4);            //  0.4 MB
    size_t o_ovfn = take(256);
    size_t o_asrc = take((size_t)N * 4);
    size_t o_adst = take((size_t)N * 4);
    size_t o_ad2  = take((size_t)N * 4);

    char* base = (char*)d_ws;
    bf16*     h1    = (bf16*)(base + o_h1);
    unsigned* bkt   = (unsigned*)(base + o_bkt);
    float*    h2p   = (float*)(base + o_h2p);
    unsigned char* rank8 = (unsigned char*)(base + o_h2p);  // alias
    uint2*    ovf   = (uint2*)(base + o_ovf);
    int*      cnt   = (int*)(base + o_cnt);
    int*      ovfn  = (int*)(base + o_ovfn);
    float*    asrc  = (float*)(base + o_asrc);
    float*    adst  = (float*)(base + o_adst);
    float*    ad2   = (float*)(base + o_ad2);

    // Cooperative grid: full co-resident capacity (occupancy-query cached).
    static int maxBlocks = 0;
    if (maxBlocks == 0) {
        int perCU = 0;
        if (hipOccupancyMaxActiveBlocksPerMultiprocessor(&perCU, f_mega, 256, 0)
                != hipSuccess || perCU <= 0)
            perCU = 2;                                   // conservative fallback
        int dev = 0, nCU = 0;
        hipGetDevice(&dev);
        if (hipDeviceGetAttribute(&nCU, hipDeviceAttributeMultiprocessorCount, dev)
                != hipSuccess || nCU <= 0)
            nCU = 256;
        maxBlocks = perCU * nCU;
    }

    void* args[] = {
        (void*)&x, (void*)&srcv, (void*)&dstv, (void*)&ew,
        (void*)&W1, (void*)&as1, (void*)&ad1, (void*)&b1,
        (void*)&W2, (void*)&a2s, (void*)&a2d, (void*)&b2,
        (void*)&h1, (void*)&bkt, (void*)&h2p, (void*)&rank8,
        (void*)&ovf, (void*)&cnt, (void*)&ovfn,
        (void*)&asrc, (void*)&adst, (void*)&ad2,
        (void*)&out, (void*)&N, (void*)&E, (void*)&T
    };
    hipLaunchCooperativeKernel((const void*)f_mega, dim3(maxBlocks), dim3(256),
                               args, 0, stream);
}

// Round 5
// 287.153 us; speedup vs baseline: 2.2066x; 2.2066x over previous
//
#include <hip/hip_runtime.h>
#include <hip/hip_bf16.h>

typedef __hip_bfloat16 bf16;

#define DEPS 1e-16f
#define CAP 32
#define OVF_MAX 131072

__device__ __forceinline__ float bfu_lo(unsigned u) { return __uint_as_float(u << 16); }
__device__ __forceinline__ float bfu_hi(unsigned u) { return __uint_as_float(u & 0xffff0000u); }

// bucket entry: (s << 15) | q, wt = q/8192 - 1.1, q in [0,32767]
__device__ __forceinline__ float dec_wt(unsigned u) {
    return (float)(u & 32767u) * (1.f / 8192.f) - 1.1f;
}

// Heterogeneous dispatch: blocks striped 4:9 between gemm role and hist role
// (R2-proven pairing: hist is atomic-latency bound with VALU+VMEM idle, gemm
// is VALU/LDS bound -> positive overlap. NEVER pair gemm with the scatter
// pass (R3: both VMEM-bound, additive-negative). NEVER fuse the scatter with
// the atomic return (R1: serializes per-thread). NEVER go cooperative
// (R4: grid.sync coherence tax across 8 XCD L2s, 2.2x regression).)
// hist role covers T = E + N entries:
//   e < E : real edge -> atomicAdd rank, stored as u8 (clamp 255)
//   e >= E: self-loop -> DIRECT store to reserved bucket slot 0, no atomic
//           (bucket order is irrelevant to the softmax sum)
__global__ __launch_bounds__(256) void f_gemm_hist(
    const float* __restrict__ x, const float* __restrict__ W1,
    const float* __restrict__ a_src, const float* __restrict__ a_dst,
    bf16* __restrict__ h1, float* __restrict__ asrc, float* __restrict__ adst,
    const int* __restrict__ dstv, int* __restrict__ cnt,
    unsigned char* __restrict__ rank8, unsigned* __restrict__ bkt,
    int N, int E, int T, int gG, int gH)
{
    __shared__ __align__(16) float xl[32 * 128];   // 16 KB
    int bid = blockIdx.x;
    int r = bid % 13, chunk = bid / 13;
    int tid = threadIdx.x;

    if (r >= 4) {                                  // ---- hist role (9/13) ----
        int hb = chunk * 9 + (r - 4);
        if (hb >= gH) return;
        int e = hb * 256 + tid;
        if (e >= T) return;
        if (e < E) {
            int d = dstv[e];
            int pos = atomicAdd(&cnt[d], 1);
            rank8[e] = (unsigned char)min(pos, 255);
        } else {                                   // self-loop: slot 0, no atomic
            int d = e - E;
            unsigned q = (unsigned)(1.1f * 8192.f + 0.5f);   // wt = 0
            bkt[(size_t)d * CAP] = ((unsigned)d << 15) | q;
        }
        return;
    }
    // ---- gemm role (4/13) ----
    int gb = chunk * 4 + r;
    if (gb >= gG) return;
    int n0 = gb * 32;
    for (int i = tid; i < 1024; i += 256) {
        int n = n0 + (i >> 5);
        float4 v = {0.f, 0.f, 0.f, 0.f};
        if (n < N) v = ((const float4*)x)[(size_t)n * 32 + (i & 31)];
        ((float4*)xl)[i] = v;
    }
    __syncthreads();
    int w = tid >> 6, c = tid & 63;
    float sa = a_src[c], da = a_dst[c];
    float acc[8] = {0.f, 0.f, 0.f, 0.f, 0.f, 0.f, 0.f, 0.f};
    const float* Wc = W1 + c;                      // column pointer, stride 64
    for (int k4 = 0; k4 < 32; ++k4) {
        float w0 = Wc[(4 * k4 + 0) * 64];
        float w1 = Wc[(4 * k4 + 1) * 64];
        float w2 = Wc[(4 * k4 + 2) * 64];
        float w3 = Wc[(4 * k4 + 3) * 64];
        #pragma unroll
        for (int i = 0; i < 8; ++i) {
            float4 xv = ((const float4*)(xl + (w * 8 + i) * 128))[k4];
            acc[i] = fmaf(xv.x, w0, fmaf(xv.y, w1,
                     fmaf(xv.z, w2, fmaf(xv.w, w3, acc[i]))));
        }
    }
    #pragma unroll
    for (int i = 0; i < 8; ++i) {
        int n = n0 + w * 8 + i;
        float a = acc[i];
        float ps = a * sa, pd = a * da;
        #pragma unroll
        for (int o = 32; o; o >>= 1) {
            ps += __shfl_xor(ps, o);
            pd += __shfl_xor(pd, o);
        }
        if (n < N) {
            h1[(size_t)n * 64 + c] = __float2bfloat16(a);
            if (c == 0) { asrc[n] = ps; adst[n] = pd; }
        }
    }
}

// ATOMIC-FREE bucket scatter, REAL edges only: pos = 1 + rank8[e]
// (slot 0 is the self-loop, placed in f_gemm_hist). Pure coalesced loads
// + one scattered store -> full memory-level parallelism.
__global__ __launch_bounds__(256) void f_scatB(
    const int* __restrict__ srcv, const int* __restrict__ dstv,
    const float* __restrict__ ew, const unsigned char* __restrict__ rank8,
    unsigned* __restrict__ bkt, uint2* __restrict__ ovf,
    int* __restrict__ ovfn, int E)
{
    int e = blockIdx.x * 256 + threadIdx.x;
    if (e >= E) return;
    int s = srcv[e], d = dstv[e];
    float wt = 1.f - 1.f / ew[e];
    unsigned q = (unsigned)((wt + 1.1f) * 8192.f + 0.5f);
    unsigned entry = ((unsigned)s << 15) | q;
    int pos = 1 + (int)rank8[e];
    if (pos < CAP) {
        bkt[(size_t)d * CAP + pos] = entry;
    } else {
        int o = atomicAdd(ovfn, 1);      // ~tens of edges device-wide
        if (o < OVF_MAX) { uint2 v; v.x = (unsigned)d; v.y = entry; ovf[o] = v; }
    }
}

// fused layer-1 aggregate + slim layer-2 epilogue. One wave per dst.
// lenf = cnt[d] + 1 (self-loop occupies slot 0; cnt counts real edges).
__global__ __launch_bounds__(256) void f_agg1(
    const int* __restrict__ cnt, const unsigned* __restrict__ bkt,
    const uint2* __restrict__ ovf, const int* __restrict__ ovfn,
    const float* __restrict__ asrc, const float* __restrict__ adst,
    const bf16* __restrict__ h1,
    const float* __restrict__ b1, const float* __restrict__ W2,
    const float* __restrict__ a2s, const float* __restrict__ a2d,
    float* __restrict__ h2p, float* __restrict__ ad2, int N)
{
    __shared__ __align__(16) float WxT[16][68];  // 4.25 KB
    __shared__ __align__(16) float b1l[64];
    __shared__ float2 eb[4][64];                 // wave-private slices
    int tid = threadIdx.x;
    if (tid < 64) {
        float us = 0.f, ud = 0.f;
        #pragma unroll
        for (int c = 0; c < 7; ++c) {
            float wv = W2[tid * 7 + c];
            WxT[c][tid] = wv;
            us = fmaf(wv, a2s[c], us);
            ud = fmaf(wv, a2d[c], ud);
        }
        WxT[7][tid] = us;
        WxT[8][tid] = ud;
        #pragma unroll
        for (int r = 9; r < 16; ++r) WxT[r][tid] = 0.f;
        b1l[tid] = b1[tid];
    }
    __syncthreads();
    int d = blockIdx.x * 4 + (tid >> 6);
    int lane = tid & 63;
    if (d >= N) return;
    int lenf = cnt[d] + 1;
    int nc = min(lenf, CAP);
    size_t r0 = (size_t)d * CAP;
    float adv = adst[d];
    int g8 = lane >> 3, l8 = lane & 7;
    float2* ebw = eb[tid >> 6];
    float acc[8] = {0.f, 0.f, 0.f, 0.f, 0.f, 0.f, 0.f, 0.f};
    float sm = 0.f;
    {
        float ea = 0.f; unsigned s = 0;
        if (lane < nc) {
            unsigned u = bkt[r0 + lane];
            s = u >> 15;
            float a = asrc[s] + adv;
            a = (a > 0.f) ? a : 0.2f * a;
            ea = __expf(a + dec_wt(u));
            sm += ea;
        }
        ebw[lane] = make_float2(ea, __uint_as_float(s));
        for (int j = 0; j < nc; j += 8) {
            float2 eq = ebw[j + g8];             // 8 addrs, 8-lane broadcast
            float e = eq.x;                      // padded slots have e==0
            unsigned sj = __float_as_uint(eq.y);
            uint4 hv = *(const uint4*)&h1[(size_t)sj * 64 + (l8 << 3)];
            acc[0] = fmaf(e, bfu_lo(hv.x), acc[0]);
            acc[1] = fmaf(e, bfu_hi(hv.x), acc[1]);
            acc[2] = fmaf(e, bfu_lo(hv.y), acc[2]);
            acc[3] = fmaf(e, bfu_hi(hv.y), acc[3]);
            acc[4] = fmaf(e, bfu_lo(hv.z), acc[4]);
            acc[5] = fmaf(e, bfu_hi(hv.z), acc[5]);
            acc[6] = fmaf(e, bfu_lo(hv.w), acc[6]);
            acc[7] = fmaf(e, bfu_hi(hv.w), acc[7]);
        }
    }
    if (lenf > CAP) {                            // rare overflow path
        int no = min(*ovfn, OVF_MAX);
        for (int i = g8; i < no; i += 8) {       // entry i -> group i&7
            uint2 ov = ovf[i];
            if ((int)ov.x == d) {
                unsigned u = ov.y;
                unsigned s = u >> 15;
                float a = asrc[s] + adv;
                a = (a > 0.f) ? a : 0.2f * a;
                float ea = __expf(a + dec_wt(u));
                if (l8 == 0) sm += ea;           // count edge exactly once
                uint4 hv = *(const uint4*)&h1[(size_t)s * 64 + (l8 << 3)];
                acc[0] = fmaf(ea, bfu_lo(hv.x), acc[0]);
                acc[1] = fmaf(ea, bfu_hi(hv.x), acc[1]);
                acc[2] = fmaf(ea, bfu_lo(hv.y), acc[2]);
                acc[3] = fmaf(ea, bfu_hi(hv.y), acc[3]);
                acc[4] = fmaf(ea, bfu_lo(hv.z), acc[4]);
                acc[5] = fmaf(ea, bfu_hi(hv.z), acc[5]);
                acc[6] = fmaf(ea, bfu_lo(hv.w), acc[6]);
                acc[7] = fmaf(ea, bfu_hi(hv.w), acc[7]);
            }
        }
    }
    #pragma unroll
    for (int o = 32; o; o >>= 1) sm += __shfl_xor(sm, o);
    #pragma unroll
    for (int k = 0; k < 8; ++k) {
        acc[k] += __shfl_xor(acc[k], 8);
        acc[k] += __shfl_xor(acc[k], 16);
        acc[k] += __shfl_xor(acc[k], 32);
    }
    float inv = 1.f / (sm + DEPS);
    int c0 = l8 << 3;
    float4 bA = *(const float4*)&b1l[c0];
    float4 bB = *(const float4*)&b1l[c0 + 4];
    float v0 = fmaxf(fmaf(acc[0], inv, bA.x), 0.f);
    float v1 = fmaxf(fmaf(acc[1], inv, bA.y), 0.f);
    float v2 = fmaxf(fmaf(acc[2], inv, bA.z), 0.f);
    float v3 = fmaxf(fmaf(acc[3], inv, bA.w), 0.f);
    float v4 = fmaxf(fmaf(acc[4], inv, bB.x), 0.f);
    float v5 = fmaxf(fmaf(acc[5], inv, bB.y), 0.f);
    float v6 = fmaxf(fmaf(acc[6], inv, bB.z), 0.f);
    float v7 = fmaxf(fmaf(acc[7], inv, bB.w), 0.f);
    float4 wA0 = *(const float4*)&WxT[g8][c0];
    float4 wA1 = *(const float4*)&WxT[g8][c0 + 4];
    float4 wB0 = *(const float4*)&WxT[g8 + 8][c0];
    float4 wB1 = *(const float4*)&WxT[g8 + 8][c0 + 4];
    float rA = fmaf(v0, wA0.x, fmaf(v1, wA0.y, fmaf(v2, wA0.z, fmaf(v3, wA0.w,
               fmaf(v4, wA1.x, fmaf(v5, wA1.y, fmaf(v6, wA1.z, v7 * wA1.w)))))));
    float rB = fmaf(v0, wB0.x, fmaf(v1, wB0.y, fmaf(v2, wB0.z, fmaf(v3, wB0.w,
               fmaf(v4, wB1.x, fmaf(v5, wB1.y, fmaf(v6, wB1.z, v7 * wB1.w)))))));
    rA += __shfl_xor(rA, 1); rA += __shfl_xor(rA, 2); rA += __shfl_xor(rA, 4);
    rB += __shfl_xor(rB, 1); rB += __shfl_xor(rB, 2); rB += __shfl_xor(rB, 4);
    if (l8 == 0) {
        h2p[(size_t)d * 8 + g8] = rA;            // slots 0..6 = h2, 7 = as2
        if (g8 == 0) ad2[d] = rB;                // output 8 = ad2
    }
}

// fused layer-2 aggregate + bias. 8 lanes per row, 8 rows per wave.
__global__ __launch_bounds__(256) void f_agg2(
    const int* __restrict__ cnt, const unsigned* __restrict__ bkt,
    const uint2* __restrict__ ovf, const int* __restrict__ ovfn,
    const float* __restrict__ h2p, const float* __restrict__ ad2,
    const float* __restrict__ b2, float* __restrict__ out, int N)
{
    __shared__ float b2l[7];
    if (threadIdx.x < 7) b2l[threadIdx.x] = b2[threadIdx.x];
    __syncthreads();
    int lane = threadIdx.x & 63;
    int wv = threadIdx.x >> 6;
    int grp = lane >> 3, l8 = lane & 7;
    int d = blockIdx.x * 32 + wv * 8 + grp;
    bool valid = d < N;
    int lenf = 0; float adv = 0.f;
    if (valid) { lenf = cnt[d] + 1; adv = ad2[d]; }
    int nc = min(lenf, CAP);
    size_t r0 = (size_t)d * CAP;
    float sm = 0.f;
    float a0 = 0.f, a1 = 0.f, a2 = 0.f, a3 = 0.f, a4 = 0.f, a5 = 0.f, a6 = 0.f;
    for (int p = l8; p < nc; p += 8) {
        unsigned u = bkt[r0 + p];
        int s = (int)(u >> 15);
        const float* hr = &h2p[(size_t)s * 8];
        float4 A = *(const float4*)hr;
        float4 B = *(const float4*)(hr + 4);
        float a = B.w + adv;
        a = (a > 0.f) ? a : 0.2f * a;
        float ea = __expf(a + dec_wt(u));
        sm += ea;
        a0 = fmaf(ea, A.x, a0); a1 = fmaf(ea, A.y, a1);
        a2 = fmaf(ea, A.z, a2); a3 = fmaf(ea, A.w, a3);
        a4 = fmaf(ea, B.x, a4); a5 = fmaf(ea, B.y, a5);
        a6 = fmaf(ea, B.z, a6);
    }
    if (lenf > CAP) {                            // rare overflow path
        int no = min(*ovfn, OVF_MAX);
        for (int i = l8; i < no; i += 8) {
            uint2 ov = ovf[i];
            if ((int)ov.x == d) {
                unsigned u = ov.y;
                int s = (int)(u >> 15);
                const float* hr = &h2p[(size_t)s * 8];
                float4 A = *(const float4*)hr;
                float4 B = *(const float4*)(hr + 4);
                float a = B.w + adv;
                a = (a > 0.f) ? a : 0.2f * a;
                float ea = __expf(a + dec_wt(u));
                sm += ea;
                a0 = fmaf(ea, A.x, a0); a1 = fmaf(ea, A.y, a1);
                a2 = fmaf(ea, A.z, a2); a3 = fmaf(ea, A.w, a3);
                a4 = fmaf(ea, B.x, a4); a5 = fmaf(ea, B.y, a5);
                a6 = fmaf(ea, B.z, a6);
            }
        }
    }
    #pragma unroll
    for (int o = 4; o; o >>= 1) {
        sm += __shfl_xor(sm, o);
        a0 += __shfl_xor(a0, o); a1 += __shfl_xor(a1, o);
        a2 += __shfl_xor(a2, o); a3 += __shfl_xor(a3, o);
        a4 += __shfl_xor(a4, o); a5 += __shfl_xor(a5, o);
        a6 += __shfl_xor(a6, o);
    }
    if (valid && l8 < 7) {
        float inv = 1.f / (sm + DEPS);
        float val = (l8 < 4) ? ((l8 < 2) ? (l8 ? a1 : a0) : ((l8 == 2) ? a2 : a3))
                             : ((l8 < 6) ? ((l8 == 4) ? a4 : a5) : a6);
        out[(size_t)d * 7 + l8] = fmaf(val, inv, b2l[l8]);
    }
}

// ============================== HOST ======================================

extern "C" void kernel_launch(void* const* d_in, const int* in_sizes, int n_in,
                              void* d_out, int out_size, void* d_ws, size_t ws_size,
                              hipStream_t stream) {
    const float* x   = (const float*)d_in[0];
    const int*   ei  = (const int*)d_in[1];
    const float* ew  = (const float*)d_in[2];
    const float* W1  = (const float*)d_in[3];
    const float* as1 = (const float*)d_in[4];
    const float* ad1 = (const float*)d_in[5];
    const float* b1  = (const float*)d_in[6];
    const float* W2  = (const float*)d_in[7];
    const float* a2s = (const float*)d_in[8];
    const float* a2d = (const float*)d_in[9];
    const float* b2  = (const float*)d_in[10];

    int N = in_sizes[0] / 128;
    int E = in_sizes[1] / 2;
    int T = E + N;
    const int* srcv = ei;
    const int* dstv = ei + E;
    float* out = (float*)d_out;

    // workspace (256B aligned): ~31.45 MB.
    // rank8 (u8, E bytes ~1.6MB) ALIASES h2p: gemm_hist writes it, scatB
    // consumes it, and only agg1 (later) writes h2p. h1 is standalone
    // (written concurrently with rank8 in the same dispatch).
    size_t A = 0;
    auto take = [&](size_t b) { size_t o = A; A = (A + b + 255) & ~(size_t)255; return o; };
    size_t o_h1   = take((size_t)N * 64 * 2);       // 12.8 MB
    size_t o_bkt  = take((size_t)N * CAP * 4);      // 12.8 MB
    size_t o_h2p  = take((size_t)N * 8 * 4);        //  3.2 MB (rank8 aliases)
    size_t o_ovf  = take((size_t)OVF_MAX * 8);      //  1.0 MB
    size_t o_cnt  = take((size_t)N * 4);            //  0.4 MB
    size_t o_ovfn = take(256);                      //  (contiguous after cnt)
    size_t o_asrc = take((size_t)N * 4);
    size_t o_adst = take((size_t)N * 4);
    size_t o_ad2  = take((size_t)N * 4);

    char* base = (char*)d_ws;
    bf16*     h1    = (bf16*)(base + o_h1);
    unsigned* bkt   = (unsigned*)(base + o_bkt);
    float*    h2p   = (float*)(base + o_h2p);
    unsigned char* rank8 = (unsigned char*)(base + o_h2p);  // alias
    uint2*    ovf   = (uint2*)(base + o_ovf);
    int*      cnt   = (int*)(base + o_cnt);
    int*      ovfn  = (int*)(base + o_ovfn);
    float*    asrc  = (float*)(base + o_asrc);
    float*    adst  = (float*)(base + o_adst);
    float*    ad2   = (float*)(base + o_ad2);

    int gG = (N + 31) / 32;                  // gemm-role blocks
    int gH = (T + 255) / 256;                // hist-role blocks (E atomic + N direct)
    int chunks = max((gG + 3) / 4, (gH + 8) / 9);
    int gridGH = chunks * 13;                // 4:9 stripe for co-residency
    int gE = (E + 255) / 256;                // scatter blocks (real edges only)

    hipMemsetAsync(cnt, 0, (size_t)N * 4 + 256, stream);   // cnt + ovfn
    f_gemm_hist<<<gridGH, 256, 0, stream>>>(x, W1, as1, ad1, h1, asrc, adst,
                                            dstv, cnt, rank8, bkt, N, E, T, gG, gH);
    f_scatB<<<gE, 256, 0, stream>>>(srcv, dstv, ew, rank8, bkt, ovf, ovfn, E);
    f_agg1 <<<(N + 3) / 4, 256, 0, stream>>>(cnt, bkt, ovf, ovfn, asrc, adst, h1,
                                             b1, W2, a2s, a2d, h2p, ad2, N);
    f_agg2 <<<(N + 31) / 32, 256, 0, stream>>>(cnt, bkt, ovf, ovfn, h2p, ad2, b2, out, N);
}

// Round 6
// 271.870 us; speedup vs baseline: 2.3307x; 1.0562x over previous
//
#include <hip/hip_runtime.h>
#include <hip/hip_bf16.h>

typedef __hip_bfloat16 bf16;

#define DEPS 1e-16f
#define CAP 32
#define OVF_MAX 131072

__device__ __forceinline__ float bfu_lo(unsigned u) { return __uint_as_float(u << 16); }
__device__ __forceinline__ float bfu_hi(unsigned u) { return __uint_as_float(u & 0xffff0000u); }

// bucket entry: (s << 15) | q, wt = q/8192 - 1.1, q in [0,32767]
__device__ __forceinline__ float dec_wt(unsigned u) {
    return (float)(u & 32767u) * (1.f / 8192.f) - 1.1f;
}

// Heterogeneous dispatch, stripe 15:4 gemm:hist (hist blocks are 8x chunkier
// than in R2/R5, so the ratio follows block counts: gG~3125 vs gH~831).
// Session rules: gemm pairs ONLY with the atomic pass (R2 +, R3 -);
// cooperative grid.sync is a 2.2x regression (R4).
//
// hist role = FUSED hist+scatter at 8 edges/thread, two-phase pipelined:
//   phase A: 8 coalesced dst/src/ew loads + 8 INDEPENDENT atomicAdds
//   phase B: one amortized wait, then 8 independent scattered bkt stores
// R1 proved 1-edge/thread fusion serializes on the atomic round-trip
// (124us); 8-deep ILP amortizes that latency across 8x the work and
// deletes the separate f_scatB dispatch (+ its ~13us gap) entirely.
// Self-loops: direct store to reserved slot 0, no atomic (R5).
__global__ __launch_bounds__(256) void f_gemm_hs(
    const float* __restrict__ x, const float* __restrict__ W1,
    const float* __restrict__ a_src, const float* __restrict__ a_dst,
    bf16* __restrict__ h1, float* __restrict__ asrc, float* __restrict__ adst,
    const int* __restrict__ srcv, const int* __restrict__ dstv,
    const float* __restrict__ ew,
    int* __restrict__ cnt, unsigned* __restrict__ bkt,
    uint2* __restrict__ ovf, int* __restrict__ ovfn,
    int N, int E, int T, int gG, int gH)
{
    __shared__ __align__(16) float xl[32 * 128];   // 16 KB
    int bid = blockIdx.x;
    int r = bid % 19, chunk = bid / 19;
    int tid = threadIdx.x;

    if (r < 4) {                                   // ---- hist role (4/19) ----
        int hb = chunk * 4 + r;
        if (hb >= gH) return;
        int e0 = hb * 2048 + tid;                  // 8 edges/thread, stride 256
        int d_[8], pos_[8], s_[8];
        float w_[8];
        // phase A: coalesced loads + independent atomics (pipelined)
        #pragma unroll
        for (int i = 0; i < 8; ++i) {
            int e = e0 + i * 256;
            d_[i] = -1; pos_[i] = 0; s_[i] = 0; w_[i] = 1.f;
            if (e < T) {
                if (e < E) {
                    d_[i] = dstv[e];
                    s_[i] = srcv[e];
                    w_[i] = ew[e];
                    pos_[i] = atomicAdd(&cnt[d_[i]], 1);
                } else {                           // self-loop: slot 0, no atomic
                    d_[i] = e - E;
                    s_[i] = d_[i];
                    pos_[i] = -1;                  // -> slot 0
                    w_[i] = -1.f;                  // marker: wt = 0
                }
            }
        }
        // phase B: independent scattered stores
        #pragma unroll
        for (int i = 0; i < 8; ++i) {
            if (d_[i] < 0) continue;
            float wt = (w_[i] < 0.f) ? 0.f : (1.f - 1.f / w_[i]);
            unsigned q = (unsigned)((wt + 1.1f) * 8192.f + 0.5f);
            unsigned entry = ((unsigned)s_[i] << 15) | q;
            int slot = 1 + pos_[i];
            if (slot < CAP) {
                bkt[(size_t)d_[i] * CAP + slot] = entry;
            } else {
                int o = atomicAdd(ovfn, 1);        // ~tens of edges device-wide
                if (o < OVF_MAX) { uint2 v; v.x = (unsigned)d_[i]; v.y = entry; ovf[o] = v; }
            }
        }
        return;
    }
    // ---- gemm role (15/19) ----
    int gb = chunk * 15 + (r - 4);
    if (gb >= gG) return;
    int n0 = gb * 32;
    for (int i = tid; i < 1024; i += 256) {
        int n = n0 + (i >> 5);
        float4 v = {0.f, 0.f, 0.f, 0.f};
        if (n < N) v = ((const float4*)x)[(size_t)n * 32 + (i & 31)];
        ((float4*)xl)[i] = v;
    }
    __syncthreads();
    int w = tid >> 6, c = tid & 63;
    float sa = a_src[c], da = a_dst[c];
    float acc[8] = {0.f, 0.f, 0.f, 0.f, 0.f, 0.f, 0.f, 0.f};
    const float* Wc = W1 + c;                      // column pointer, stride 64
    for (int k4 = 0; k4 < 32; ++k4) {
        float w0 = Wc[(4 * k4 + 0) * 64];
        float w1 = Wc[(4 * k4 + 1) * 64];
        float w2 = Wc[(4 * k4 + 2) * 64];
        float w3 = Wc[(4 * k4 + 3) * 64];
        #pragma unroll
        for (int i = 0; i < 8; ++i) {
            float4 xv = ((const float4*)(xl + (w * 8 + i) * 128))[k4];
            acc[i] = fmaf(xv.x, w0, fmaf(xv.y, w1,
                     fmaf(xv.z, w2, fmaf(xv.w, w3, acc[i]))));
        }
    }
    #pragma unroll
    for (int i = 0; i < 8; ++i) {
        int n = n0 + w * 8 + i;
        float a = acc[i];
        float ps = a * sa, pd = a * da;
        #pragma unroll
        for (int o = 32; o; o >>= 1) {
            ps += __shfl_xor(ps, o);
            pd += __shfl_xor(pd, o);
        }
        if (n < N) {
            h1[(size_t)n * 64 + c] = __float2bfloat16(a);
            if (c == 0) { asrc[n] = ps; adst[n] = pd; }
        }
    }
}

// fused layer-1 aggregate + slim layer-2 epilogue. One wave per dst.
// lenf = cnt[d] + 1 (self-loop occupies slot 0; cnt counts real edges).
__global__ __launch_bounds__(256) void f_agg1(
    const int* __restrict__ cnt, const unsigned* __restrict__ bkt,
    const uint2* __restrict__ ovf, const int* __restrict__ ovfn,
    const float* __restrict__ asrc, const float* __restrict__ adst,
    const bf16* __restrict__ h1,
    const float* __restrict__ b1, const float* __restrict__ W2,
    const float* __restrict__ a2s, const float* __restrict__ a2d,
    float* __restrict__ h2p, float* __restrict__ ad2, int N)
{
    __shared__ __align__(16) float WxT[16][68];  // 4.25 KB
    __shared__ __align__(16) float b1l[64];
    __shared__ float2 eb[4][64];                 // wave-private slices
    int tid = threadIdx.x;
    if (tid < 64) {
        float us = 0.f, ud = 0.f;
        #pragma unroll
        for (int c = 0; c < 7; ++c) {
            float wv = W2[tid * 7 + c];
            WxT[c][tid] = wv;
            us = fmaf(wv, a2s[c], us);
            ud = fmaf(wv, a2d[c], ud);
        }
        WxT[7][tid] = us;
        WxT[8][tid] = ud;
        #pragma unroll
        for (int r = 9; r < 16; ++r) WxT[r][tid] = 0.f;
        b1l[tid] = b1[tid];
    }
    __syncthreads();
    int d = blockIdx.x * 4 + (tid >> 6);
    int lane = tid & 63;
    if (d >= N) return;
    int lenf = cnt[d] + 1;
    int nc = min(lenf, CAP);
    size_t r0 = (size_t)d * CAP;
    float adv = adst[d];
    int g8 = lane >> 3, l8 = lane & 7;
    float2* ebw = eb[tid >> 6];
    float acc[8] = {0.f, 0.f, 0.f, 0.f, 0.f, 0.f, 0.f, 0.f};
    float sm = 0.f;
    {
        float ea = 0.f; unsigned s = 0;
        if (lane < nc) {
            unsigned u = bkt[r0 + lane];
            s = u >> 15;
            float a = asrc[s] + adv;
            a = (a > 0.f) ? a : 0.2f * a;
            ea = __expf(a + dec_wt(u));
            sm += ea;
        }
        ebw[lane] = make_float2(ea, __uint_as_float(s));
        for (int j = 0; j < nc; j += 8) {
            float2 eq = ebw[j + g8];             // 8 addrs, 8-lane broadcast
            float e = eq.x;                      // padded slots have e==0
            unsigned sj = __float_as_uint(eq.y);
            uint4 hv = *(const uint4*)&h1[(size_t)sj * 64 + (l8 << 3)];
            acc[0] = fmaf(e, bfu_lo(hv.x), acc[0]);
            acc[1] = fmaf(e, bfu_hi(hv.x), acc[1]);
            acc[2] = fmaf(e, bfu_lo(hv.y), acc[2]);
            acc[3] = fmaf(e, bfu_hi(hv.y), acc[3]);
            acc[4] = fmaf(e, bfu_lo(hv.z), acc[4]);
            acc[5] = fmaf(e, bfu_hi(hv.z), acc[5]);
            acc[6] = fmaf(e, bfu_lo(hv.w), acc[6]);
            acc[7] = fmaf(e, bfu_hi(hv.w), acc[7]);
        }
    }
    if (lenf > CAP) {                            // rare overflow path
        int no = min(*ovfn, OVF_MAX);
        for (int i = g8; i < no; i += 8) {       // entry i -> group i&7
            uint2 ov = ovf[i];
            if ((int)ov.x == d) {
                unsigned u = ov.y;
                unsigned s = u >> 15;
                float a = asrc[s] + adv;
                a = (a > 0.f) ? a : 0.2f * a;
                float ea = __expf(a + dec_wt(u));
                if (l8 == 0) sm += ea;           // count edge exactly once
                uint4 hv = *(const uint4*)&h1[(size_t)s * 64 + (l8 << 3)];
                acc[0] = fmaf(ea, bfu_lo(hv.x), acc[0]);
                acc[1] = fmaf(ea, bfu_hi(hv.x), acc[1]);
                acc[2] = fmaf(ea, bfu_lo(hv.y), acc[2]);
                acc[3] = fmaf(ea, bfu_hi(hv.y), acc[3]);
                acc[4] = fmaf(ea, bfu_lo(hv.z), acc[4]);
                acc[5] = fmaf(ea, bfu_hi(hv.z), acc[5]);
                acc[6] = fmaf(ea, bfu_lo(hv.w), acc[6]);
                acc[7] = fmaf(ea, bfu_hi(hv.w), acc[7]);
            }
        }
    }
    #pragma unroll
    for (int o = 32; o; o >>= 1) sm += __shfl_xor(sm, o);
    #pragma unroll
    for (int k = 0; k < 8; ++k) {
        acc[k] += __shfl_xor(acc[k], 8);
        acc[k] += __shfl_xor(acc[k], 16);
        acc[k] += __shfl_xor(acc[k], 32);
    }
    float inv = 1.f / (sm + DEPS);
    int c0 = l8 << 3;
    float4 bA = *(const float4*)&b1l[c0];
    float4 bB = *(const float4*)&b1l[c0 + 4];
    float v0 = fmaxf(fmaf(acc[0], inv, bA.x), 0.f);
    float v1 = fmaxf(fmaf(acc[1], inv, bA.y), 0.f);
    float v2 = fmaxf(fmaf(acc[2], inv, bA.z), 0.f);
    float v3 = fmaxf(fmaf(acc[3], inv, bA.w), 0.f);
    float v4 = fmaxf(fmaf(acc[4], inv, bB.x), 0.f);
    float v5 = fmaxf(fmaf(acc[5], inv, bB.y), 0.f);
    float v6 = fmaxf(fmaf(acc[6], inv, bB.z), 0.f);
    float v7 = fmaxf(fmaf(acc[7], inv, bB.w), 0.f);
    float4 wA0 = *(const float4*)&WxT[g8][c0];
    float4 wA1 = *(const float4*)&WxT[g8][c0 + 4];
    float4 wB0 = *(const float4*)&WxT[g8 + 8][c0];
    float4 wB1 = *(const float4*)&WxT[g8 + 8][c0 + 4];
    float rA = fmaf(v0, wA0.x, fmaf(v1, wA0.y, fmaf(v2, wA0.z, fmaf(v3, wA0.w,
               fmaf(v4, wA1.x, fmaf(v5, wA1.y, fmaf(v6, wA1.z, v7 * wA1.w)))))));
    float rB = fmaf(v0, wB0.x, fmaf(v1, wB0.y, fmaf(v2, wB0.z, fmaf(v3, wB0.w,
               fmaf(v4, wB1.x, fmaf(v5, wB1.y, fmaf(v6, wB1.z, v7 * wB1.w)))))));
    rA += __shfl_xor(rA, 1); rA += __shfl_xor(rA, 2); rA += __shfl_xor(rA, 4);
    rB += __shfl_xor(rB, 1); rB += __shfl_xor(rB, 2); rB += __shfl_xor(rB, 4);
    if (l8 == 0) {
        h2p[(size_t)d * 8 + g8] = rA;            // slots 0..6 = h2, 7 = as2
        if (g8 == 0) ad2[d] = rB;                // output 8 = ad2
    }
}

// fused layer-2 aggregate + bias. 8 lanes per row, 8 rows per wave.
__global__ __launch_bounds__(256) void f_agg2(
    const int* __restrict__ cnt, const unsigned* __restrict__ bkt,
    const uint2* __restrict__ ovf, const int* __restrict__ ovfn,
    const float* __restrict__ h2p, const float* __restrict__ ad2,
    const float* __restrict__ b2, float* __restrict__ out, int N)
{
    __shared__ float b2l[7];
    if (threadIdx.x < 7) b2l[threadIdx.x] = b2[threadIdx.x];
    __syncthreads();
    int lane = threadIdx.x & 63;
    int wv = threadIdx.x >> 6;
    int grp = lane >> 3, l8 = lane & 7;
    int d = blockIdx.x * 32 + wv * 8 + grp;
    bool valid = d < N;
    int lenf = 0; float adv = 0.f;
    if (valid) { lenf = cnt[d] + 1; adv = ad2[d]; }
    int nc = min(lenf, CAP);
    size_t r0 = (size_t)d * CAP;
    float sm = 0.f;
    float a0 = 0.f, a1 = 0.f, a2 = 0.f, a3 = 0.f, a4 = 0.f, a5 = 0.f, a6 = 0.f;
    for (int p = l8; p < nc; p += 8) {
        unsigned u = bkt[r0 + p];
        int s = (int)(u >> 15);
        const float* hr = &h2p[(size_t)s * 8];
        float4 A = *(const float4*)hr;
        float4 B = *(const float4*)(hr + 4);
        float a = B.w + adv;
        a = (a > 0.f) ? a : 0.2f * a;
        float ea = __expf(a + dec_wt(u));
        sm += ea;
        a0 = fmaf(ea, A.x, a0); a1 = fmaf(ea, A.y, a1);
        a2 = fmaf(ea, A.z, a2); a3 = fmaf(ea, A.w, a3);
        a4 = fmaf(ea, B.x, a4); a5 = fmaf(ea, B.y, a5);
        a6 = fmaf(ea, B.z, a6);
    }
    if (lenf > CAP) {                            // rare overflow path
        int no = min(*ovfn, OVF_MAX);
        for (int i = l8; i < no; i += 8) {
            uint2 ov = ovf[i];
            if ((int)ov.x == d) {
                unsigned u = ov.y;
                int s = (int)(u >> 15);
                const float* hr = &h2p[(size_t)s * 8];
                float4 A = *(const float4*)hr;
                float4 B = *(const float4*)(hr + 4);
                float a = B.w + adv;
                a = (a > 0.f) ? a : 0.2f * a;
                float ea = __expf(a + dec_wt(u));
                sm += ea;
                a0 = fmaf(ea, A.x, a0); a1 = fmaf(ea, A.y, a1);
                a2 = fmaf(ea, A.z, a2); a3 = fmaf(ea, A.w, a3);
                a4 = fmaf(ea, B.x, a4); a5 = fmaf(ea, B.y, a5);
                a6 = fmaf(ea, B.z, a6);
            }
        }
    }
    #pragma unroll
    for (int o = 4; o; o >>= 1) {
        sm += __shfl_xor(sm, o);
        a0 += __shfl_xor(a0, o); a1 += __shfl_xor(a1, o);
        a2 += __shfl_xor(a2, o); a3 += __shfl_xor(a3, o);
        a4 += __shfl_xor(a4, o); a5 += __shfl_xor(a5, o);
        a6 += __shfl_xor(a6, o);
    }
    if (valid && l8 < 7) {
        float inv = 1.f / (sm + DEPS);
        float val = (l8 < 4) ? ((l8 < 2) ? (l8 ? a1 : a0) : ((l8 == 2) ? a2 : a3))
                             : ((l8 < 6) ? ((l8 == 4) ? a4 : a5) : a6);
        out[(size_t)d * 7 + l8] = fmaf(val, inv, b2l[l8]);
    }
}

// ============================== HOST ======================================

extern "C" void kernel_launch(void* const* d_in, const int* in_sizes, int n_in,
                              void* d_out, int out_size, void* d_ws, size_t ws_size,
                              hipStream_t stream) {
    const float* x   = (const float*)d_in[0];
    const int*   ei  = (const int*)d_in[1];
    const float* ew  = (const float*)d_in[2];
    const float* W1  = (const float*)d_in[3];
    const float* as1 = (const float*)d_in[4];
    const float* ad1 = (const float*)d_in[5];
    const float* b1  = (const float*)d_in[6];
    const float* W2  = (const float*)d_in[7];
    const float* a2s = (const float*)d_in[8];
    const float* a2d = (const float*)d_in[9];
    const float* b2  = (const float*)d_in[10];

    int N = in_sizes[0] / 128;
    int E = in_sizes[1] / 2;
    int T = E + N;
    const int* srcv = ei;
    const int* dstv = ei + E;
    float* out = (float*)d_out;

    // workspace (256B aligned): ~31.45 MB. rank8 no longer exists (fused
    // hist+scatter consumes atomic returns in-register).
    size_t A = 0;
    auto take = [&](size_t b) { size_t o = A; A = (A + b + 255) & ~(size_t)255; return o; };
    size_t o_h1   = take((size_t)N * 64 * 2);       // 12.8 MB
    size_t o_bkt  = take((size_t)N * CAP * 4);      // 12.8 MB
    size_t o_h2p  = take((size_t)N * 8 * 4);        //  3.2 MB padded (+as2)
    size_t o_ovf  = take((size_t)OVF_MAX * 8);      //  1.0 MB
    size_t o_cnt  = take((size_t)N * 4);            //  0.4 MB
    size_t o_ovfn = take(256);                      //  (contiguous after cnt)
    size_t o_asrc = take((size_t)N * 4);
    size_t o_adst = take((size_t)N * 4);
    size_t o_ad2  = take((size_t)N * 4);

    char* base = (char*)d_ws;
    bf16*     h1    = (bf16*)(base + o_h1);
    unsigned* bkt   = (unsigned*)(base + o_bkt);
    float*    h2p   = (float*)(base + o_h2p);
    uint2*    ovf   = (uint2*)(base + o_ovf);
    int*      cnt   = (int*)(base + o_cnt);
    int*      ovfn  = (int*)(base + o_ovfn);
    float*    asrc  = (float*)(base + o_asrc);
    float*    adst  = (float*)(base + o_adst);
    float*    ad2   = (float*)(base + o_ad2);

    int gG = (N + 31) / 32;                  // gemm-role blocks (~3125)
    int gH = (T + 2047) / 2048;              // fused hist+scat blocks (~831)
    int chunks = max((gG + 14) / 15, (gH + 3) / 4);
    int gridGH = chunks * 19;                // 15:4 stripe for co-residency

    hipMemsetAsync(cnt, 0, (size_t)N * 4 + 256, stream);   // cnt + ovfn
    f_gemm_hs<<<gridGH, 256, 0, stream>>>(x, W1, as1, ad1, h1, asrc, adst,
                                          srcv, dstv, ew, cnt, bkt, ovf, ovfn,
                                          N, E, T, gG, gH);
    f_agg1 <<<(N + 3) / 4, 256, 0, stream>>>(cnt, bkt, ovf, ovfn, asrc, adst, h1,
                                             b1, W2, a2s, a2d, h2p, ad2, N);
    f_agg2 <<<(N + 31) / 32, 256, 0, stream>>>(cnt, bkt, ovf, ovfn, h2p, ad2, b2, out, N);
}